// Round 4
// baseline (113.357 us; speedup 1.0000x reference)
//
#include <hip/hip_runtime.h>

// out[b,0,i,j] = sigmoid(cos(pi*x[b,0,i,j] + w[0]) - thr[0]),  i,j in [0,510)
// x: (64,1,512,512) fp32, out: (64,1,510,510) fp32. Memory-bound elementwise.
//
// Layout: 1 block (256 thr) = 4 output rows; 128 threads cover one row with
// dwordx4. Each thread handles TWO rows (r0 = blk*4 + (t>>7), r0+2) at the
// same column -> 2 independent load/store pairs in flight (MLP=2) while
// wave-level coalescing stays perfect. Thread 127 clamps to col 506: cols
// 506/507 written twice with identical bits (benign).

#define BATCH 64
#define H_IN 512
#define W_IN 512
#define H_OUT 510
#define W_OUT 510
#define ROWS_TOTAL (BATCH * H_OUT)        // 32640
#define ROWS_PER_BLOCK 4

struct f4 { float x, y, z, w; };

__device__ __forceinline__ f4 eval4(const f4 v, float w0, float thr) {
    const float PI = 3.14159265358979323846f;
    f4 r;
    #pragma unroll
    for (int k = 0; k < 4; ++k) {
        const float xv = (&v.x)[k];
        const float c  = __cosf(fmaf(xv, PI, w0));
        const float e  = __expf(thr - c);
        (&r.x)[k] = __builtin_amdgcn_rcpf(1.0f + e);          // sigmoid(c - thr)
    }
    return r;
}

__global__ void __launch_bounds__(256) conv154_kernel(
        const float* __restrict__ x,
        const float* __restrict__ weight,
        const float* __restrict__ threshold,
        float* __restrict__ out) {
    const float w0  = weight[0];
    const float thr = threshold[0];

    const int t    = threadIdx.x;
    const int row0 = blockIdx.x * ROWS_PER_BLOCK + (t >> 7);  // rows row0, row0+2
    const int row1 = row0 + 2;
    const int j    = t & 127;
    int col = j * 4;
    if (col > W_OUT - 4) col = W_OUT - 4;                     // 506: overlap tail

    const int b0 = row0 / H_OUT;          // magic-mul
    const int i0 = row0 - b0 * H_OUT;
    const int b1 = row1 / H_OUT;
    const int i1 = row1 - b1 * H_OUT;

    const float* in0  = x   + (size_t)b0 * (H_IN * W_IN) + (size_t)i0 * W_IN + col;
    const float* in1  = x   + (size_t)b1 * (H_IN * W_IN) + (size_t)i1 * W_IN + col;
    float*       out0 = out + (size_t)row0 * W_OUT + col;
    float*       out1 = out + (size_t)row1 * W_OUT + col;

    // Issue both loads before any dependent compute (MLP=2).
    const f4 v0 = *reinterpret_cast<const f4*>(in0);
    const f4 v1 = *reinterpret_cast<const f4*>(in1);

    const f4 r0 = eval4(v0, w0, thr);
    const f4 r1 = eval4(v1, w0, thr);

    *reinterpret_cast<f4*>(out0) = r0;
    *reinterpret_cast<f4*>(out1) = r1;
}

extern "C" void kernel_launch(void* const* d_in, const int* in_sizes, int n_in,
                              void* d_out, int out_size, void* d_ws, size_t ws_size,
                              hipStream_t stream) {
    const float* x   = (const float*)d_in[0];
    const float* w   = (const float*)d_in[1];
    const float* thr = (const float*)d_in[2];
    float* out       = (float*)d_out;

    const int grid = ROWS_TOTAL / ROWS_PER_BLOCK;   // 8160 blocks, exact
    conv154_kernel<<<grid, 256, 0, stream>>>(x, w, thr, out);
}